// Round 12
// baseline (248.597 us; speedup 1.0000x reference)
//
#include <hip/hip_runtime.h>
#include <hip/hip_bf16.h>
#include <math.h>

// DiscriminationLoss via MFMA (R12):
//   S[k,c] = sum_{p: label[p]=k} pred[c,p],  N[k] = |{p: label[p]=k}|, k=1..32
//   A[k]   = N[k] * sum_c S[k,c]^2
//   L      = sum_{i<j} log(max(3 - sqrt(A_i + A_j), 0)^2 + 1);  out = L*(K-1)/K
//
// R11 lesson: trailing-block fusion = __threadfence() (buffer_wbl2, an L2
// writeback) per block x 1024 + 295K device-atomic burst => 215us. Reverted
// to R10's 3-kernel plain-store structure (45.7us known good).
// R12 change: hide latency with OCCUPANCY not pipeline depth:
//   NBLK=2048 + __launch_bounds__(256,8) -> 32 waves/CU (HW max);
//   pipeline shrunk to 2-deep so VGPR <= 64 (8-wave budget, no spill).

typedef __attribute__((ext_vector_type(8))) short short8;
typedef __attribute__((ext_vector_type(4))) float f32x4;

constexpr int NSEGF = 32;            // segments 1..32 (label 0 = background, dropped)
constexpr int RPS   = 9;             // 8 channels + count
constexpr int NROWS = NSEGF * RPS;   // 288
constexpr int BLK   = 256;
constexpr int WPB   = 4;
constexpr int NBLK  = 2048;          // 8 blocks/CU, exactly co-resident
constexpr int NWAVE = NBLK * WPB;    // 8192 waves
constexpr int PXS   = 32;            // pixels per k-step (K of 16x16x32)
constexpr int L1BLK = 32;            // level-1 reduce blocks
constexpr int SLABS = NBLK / L1BLK;  // 64 slabs per reduce block
constexpr int L1BASE   = 1024;       // ws float offset of level-1 partials [row][block]
constexpr int PARTBASE = 16384;      // ws float offset of per-block slabs [block][row]

#define SCHED_FENCE asm volatile("" ::: "memory")

__device__ __forceinline__ short f2bf(float f) {
  return (short)__bfloat16_as_ushort(__float2bfloat16(f));
}

__device__ __forceinline__ float wave_sum64(float x) {
  int t;
  t = __builtin_amdgcn_update_dpp(0, __float_as_int(x), 0x111, 0xf, 0xf, true); x += __int_as_float(t);
  t = __builtin_amdgcn_update_dpp(0, __float_as_int(x), 0x112, 0xf, 0xf, true); x += __int_as_float(t);
  t = __builtin_amdgcn_update_dpp(0, __float_as_int(x), 0x114, 0xf, 0xf, true); x += __int_as_float(t);
  t = __builtin_amdgcn_update_dpp(0, __float_as_int(x), 0x118, 0xf, 0xf, true); x += __int_as_float(t);
  t = __builtin_amdgcn_update_dpp(0, __float_as_int(x), 0x142, 0xf, 0xf, true); x += __int_as_float(t);
  t = __builtin_amdgcn_update_dpp(0, __float_as_int(x), 0x143, 0xf, 0xf, true); x += __int_as_float(t);
  return x;  // lane 63 holds the sum
}

// Load one k-step's operands into named registers. KIDX is wave-uniform
// (scalar); only the dead prefetch tail is clamped.
#define LOADSET(PA, PB, LA, LB, KIDX)                                          \
  {                                                                            \
    int kc_ = (KIDX); if (kc_ > lastk) kc_ = lastk;                            \
    const size_t off_ = (size_t)kc_ * PXS;                                     \
    if (isch) {                                                                \
      PA = *(const float4*)(pc + off_);                                        \
      PB = *(const float4*)(pc + off_ + 4);                                    \
    }                                                                          \
    LA = *(const int4*)(lp + off_);                                            \
    LB = *(const int4*)(lp + off_ + 4);                                        \
  }

#define COMPSET(PA, PB, LA, LB)                                                \
  {                                                                            \
    short8 A0_, A1_, B_;                                                       \
    A0_[0] = (LA.x == ms0) ? ONE : (short)0;                                   \
    A0_[1] = (LA.y == ms0) ? ONE : (short)0;                                   \
    A0_[2] = (LA.z == ms0) ? ONE : (short)0;                                   \
    A0_[3] = (LA.w == ms0) ? ONE : (short)0;                                   \
    A0_[4] = (LB.x == ms0) ? ONE : (short)0;                                   \
    A0_[5] = (LB.y == ms0) ? ONE : (short)0;                                   \
    A0_[6] = (LB.z == ms0) ? ONE : (short)0;                                   \
    A0_[7] = (LB.w == ms0) ? ONE : (short)0;                                   \
    A1_[0] = (LA.x == ms1) ? ONE : (short)0;                                   \
    A1_[1] = (LA.y == ms1) ? ONE : (short)0;                                   \
    A1_[2] = (LA.z == ms1) ? ONE : (short)0;                                   \
    A1_[3] = (LA.w == ms1) ? ONE : (short)0;                                   \
    A1_[4] = (LB.x == ms1) ? ONE : (short)0;                                   \
    A1_[5] = (LB.y == ms1) ? ONE : (short)0;                                   \
    A1_[6] = (LB.z == ms1) ? ONE : (short)0;                                   \
    A1_[7] = (LB.w == ms1) ? ONE : (short)0;                                   \
    if (isch) {                                                                \
      B_[0] = f2bf(PA.x); B_[1] = f2bf(PA.y);                                  \
      B_[2] = f2bf(PA.z); B_[3] = f2bf(PA.w);                                  \
      B_[4] = f2bf(PB.x); B_[5] = f2bf(PB.y);                                  \
      B_[6] = f2bf(PB.z); B_[7] = f2bf(PB.w);                                  \
    } else {                                                                   \
      B_ = Bconst;                                                             \
    }                                                                          \
    acc0 = __builtin_amdgcn_mfma_f32_16x16x32_bf16(A0_, B_, acc0, 0, 0, 0);    \
    acc1 = __builtin_amdgcn_mfma_f32_16x16x32_bf16(A1_, B_, acc1, 0, 0, 0);    \
  }

__global__ __launch_bounds__(BLK, 8)
void seg_mfma(const float* __restrict__ pred,
              const int*   __restrict__ lab,
              float*       __restrict__ ws,
              int P) {
  __shared__ float red[WPB][NROWS];
  const int tid  = threadIdx.x;
  const int wid  = tid >> 6;
  const int lane = tid & 63;
  const int colq = lane & 15;   // D col: 0..7 channel, 8 count, 9..15 unused
  const int quad = lane >> 4;   // k-group (8 px each)
  const int ms0  = colq + 1;    // acc0: segments 1..16
  const int ms1  = colq + 17;   // acc1: segments 17..32
  const short ONE = (short)0x3F80;

  // XCD-bijective block swizzle: XCD x owns a contiguous 1/8 of the data.
  const int bs = (blockIdx.x & 7) * (NBLK / 8) + (blockIdx.x >> 3);
  const int gw = bs * WPB + wid;

  const int nsteps = P / PXS;
  const int spw    = nsteps / NWAVE;     // contiguous steps per wave (guarded %2==0)
  const int kbase  = gw * spw;
  const int lastk  = nsteps - 1;
  const bool isch  = (colq < 8);
  const float* pc = pred + (size_t)(colq & 7) * P + quad * 8;
  const int*   lp = lab + quad * 8;

  f32x4 acc0 = {0.f, 0.f, 0.f, 0.f};
  f32x4 acc1 = {0.f, 0.f, 0.f, 0.f};

  short8 Bconst;   // col 8 -> bf16 1.0 (counts); cols 9..15 -> 0
  {
    const short v = (colq == 8) ? ONE : (short)0;
#pragma unroll
    for (int i = 0; i < 8; ++i) Bconst[i] = v;
  }

  float4 pa0 = {}, pb0 = {}, pa1 = {}, pb1 = {};
  int4   la0, lb0, la1, lb1;

  int k = kbase;
  LOADSET(pa0, pb0, la0, lb0, k)
  LOADSET(pa1, pb1, la1, lb1, k + 1)

  for (int i = 0; i < spw; i += 2) {
    SCHED_FENCE;
    COMPSET(pa0, pb0, la0, lb0)
    LOADSET(pa0, pb0, la0, lb0, k + 2)
    SCHED_FENCE;
    COMPSET(pa1, pb1, la1, lb1)
    LOADSET(pa1, pb1, la1, lb1, k + 3)
    k += 2;
  }

  // D layout (m89/m91-verified): col = lane&15, row = (lane>>4)*4 + reg.
  // acc0 row r -> segment r+1 ; acc1 row r -> segment r+17.
  if (colq < RPS) {
#pragma unroll
    for (int r = 0; r < 4; ++r)
      red[wid][(quad * 4 + r) * RPS + colq] = acc0[r];
#pragma unroll
    for (int r = 0; r < 4; ++r)
      red[wid][(16 + quad * 4 + r) * RPS + colq] = acc1[r];
  }
  __syncthreads();
  for (int v = tid; v < NROWS; v += BLK) {
    float s = 0.f;
#pragma unroll
    for (int w = 0; w < WPB; ++w) s += red[w][v];
    ws[PARTBASE + (size_t)blockIdx.x * NROWS + v] = s;   // plain-store slab
  }
}

// Level-1: block b sums SLABS contiguous slabs (coalesced reads); writes
// TRANSPOSED [row][block] so finish reads 128B-contiguous rows.
__global__ __launch_bounds__(256)
void reduce1(float* __restrict__ ws) {
  const int b = blockIdx.x;
  for (int v = threadIdx.x; v < NROWS; v += 256) {
    float s = 0.f;
#pragma unroll 4
    for (int i = 0; i < SLABS; ++i)
      s += ws[PARTBASE + (size_t)(b * SLABS + i) * NROWS + v];
    ws[L1BASE + (size_t)v * L1BLK + b] = s;
  }
}

// Fallback (C != 8 or bad divisibility): LDS-atomic bins, plain-store slabs.
__global__ __launch_bounds__(BLK)
void seg_gen(const float* __restrict__ pred,
             const int*   __restrict__ lab,
             float*       __restrict__ ws,
             int P, int C) {
  __shared__ float bins[(NSEGF + 1) * RPS];
  const int tid = threadIdx.x;
  for (int i = tid; i < (NSEGF + 1) * RPS; i += BLK) bins[i] = 0.f;
  __syncthreads();
  const int stride = gridDim.x * BLK;
  const int Cc = C < 8 ? C : 8;
  for (int p = blockIdx.x * BLK + tid; p < P; p += stride) {
    int lb = lab[p]; if (lb < 0) lb = 0; if (lb > NSEGF) lb = NSEGF;
    const int o = lb * RPS;
    unsafeAtomicAdd(&bins[o + 8], 1.f);
    for (int c = 0; c < Cc; ++c)
      unsafeAtomicAdd(&bins[o + c], pred[(size_t)c * P + p]);
  }
  __syncthreads();
  for (int i = tid; i < NROWS; i += BLK)
    ws[PARTBASE + (size_t)blockIdx.x * NROWS + i] = bins[RPS + i];
}

__global__ __launch_bounds__(256)
void finish_kernel(const float* __restrict__ ws,
                   const int*   __restrict__ nkp,
                   float*       __restrict__ out,
                   int C) {
  __shared__ float sfin[NROWS];
  __shared__ float sA[NSEGF + 1];
  __shared__ float wsum[4];
  int K = *nkp; if (K > NSEGF) K = NSEGF;
  const int tid = threadIdx.x;
  const int Cc = C < 8 ? C : 8;

  // Level-2 reduce: row v's 32 partials are contiguous (128B) -> coalesced.
  for (int v = tid; v < NROWS; v += 256) {
    const float* r = ws + L1BASE + (size_t)v * L1BLK;
    float s = 0.f;
#pragma unroll
    for (int b = 0; b < L1BLK; ++b) s += r[b];
    sfin[v] = s;
  }
  __syncthreads();
  for (int k = 1 + tid; k <= K; k += 256) {
    float s2 = 0.f;
    for (int c = 0; c < Cc; ++c) {
      const float v = sfin[(k - 1) * RPS + c];
      s2 = fmaf(v, v, s2);
    }
    sA[k] = sfin[(k - 1) * RPS + 8] * s2;
  }
  __syncthreads();

  // All-lane pair loop across 256 threads (~2 pairs/thread).
  const int npairs = K * (K - 1) / 2;
  float accv = 0.f;
  for (int idx = tid; idx < npairs; idx += 256) {
    int i = 1, rem = idx;
    while (rem >= K - i) { rem -= K - i; ++i; }
    const int j = i + 1 + rem;
    const float ps = sA[i] + sA[j];
    const float d  = fmaxf(3.0f - sqrtf(ps), 0.f);
    accv += logf(fmaf(d, d, 1.f));
  }
  accv = wave_sum64(accv);
  if ((tid & 63) == 63) wsum[tid >> 6] = accv;
  __syncthreads();
  if (tid == 0)
    out[0] = (wsum[0] + wsum[1] + wsum[2] + wsum[3]) * (float)(K - 1) / (float)K;
}

extern "C" void kernel_launch(void* const* d_in, const int* in_sizes, int n_in,
                              void* d_out, int out_size, void* d_ws, size_t ws_size,
                              hipStream_t stream) {
  const float* pred = (const float*)d_in[0];
  const int*   lab  = (const int*)d_in[2];
  const int*   nkp  = (const int*)d_in[3];
  float*       out  = (float*)d_out;
  float*       ws   = (float*)d_ws;

  const int P = in_sizes[2];        // H*W
  const int C = in_sizes[0] / P;    // channels

  const size_t need = (size_t)(PARTBASE + (size_t)NBLK * NROWS) * sizeof(float);
  const int spw = (P / PXS) / NWAVE;
  const bool fast = (C == 8) && (P % (PXS * NWAVE)) == 0 &&
                    spw >= 2 && (spw & 1) == 0 && ws_size >= need;

  if (fast) {
    seg_mfma<<<NBLK, BLK, 0, stream>>>(pred, lab, ws, P);
  } else {
    seg_gen<<<NBLK, BLK, 0, stream>>>(pred, lab, ws, P, C);
  }
  reduce1<<<L1BLK, 256, 0, stream>>>(ws);
  finish_kernel<<<1, 256, 0, stream>>>(ws, nkp, out, C);
}

// Round 13
// 46.692 us; speedup vs baseline: 5.3242x; 5.3242x over previous
//
#include <hip/hip_runtime.h>
#include <hip/hip_bf16.h>
#include <math.h>

// DiscriminationLoss via MFMA (R13):
//   S[k,c] = sum_{p: label[p]=k} pred[c,p],  N[k] = |{p: label[p]=k}|, k=1..32
//   A[k]   = N[k] * sum_c S[k,c]^2
//   L      = sum_{i<j} log(max(3 - sqrt(A_i + A_j), 0)^2 + 1);  out = L*(K-1)/K
//
// R12 lesson: launch_bounds(256,8) (64 VGPR cap) + register pipeline = scratch
// spills (WRITE 147MB, 64x). Register prefetch depth and occupancy are
// mutually exclusive. R13 moves in-flight bytes to LDS via global_load_lds
// DMA (zero VGPR cost) with counted vmcnt (T3/T4):
//   - 512 blocks (2/CU, 76.6KB LDS), per-WAVE private double-buffered 256-px
//     tiles: 8 pred-channel rows (1KB each) + 1KB labels = 9 DMA instrs/tile.
//   - schedule: stage(t+2); vmcnt(9); compute(t)  -> 1 tile-compute of slack,
//     never vmcnt(0) in steady state, no barriers (per-wave buffers).
//   - pred LDS rows XOR-swizzled (byte ^ ((ch&3)<<5)); DMA dest linear,
//     global SOURCE pre-swizzled, ds_read swizzled (rule #21) -> 8-way bank
//     conflict becomes free 2-way.
//   - compute math (dual 16x16x32 one-hot MFMA) identical to R8-R12 (passed).

typedef __attribute__((ext_vector_type(8))) short short8;
typedef __attribute__((ext_vector_type(4))) float f32x4;

constexpr int NSEGF = 32;            // segments 1..32 (label 0 = background)
constexpr int RPS   = 9;             // 8 channels + count
constexpr int NROWS = NSEGF * RPS;   // 288
constexpr int BLK   = 256;
constexpr int WPB   = 4;
constexpr int NBLK  = 512;           // 2 blocks/CU exactly co-resident
constexpr int NWAVES= NBLK * WPB;    // 2048 waves
constexpr int TPX   = 256;           // pixels per tile (per wave per buffer)
constexpr int STEPS = TPX / 32;      // 8 dual-MFMA steps per tile
constexpr int L1BLK = 32;            // level-1 reduce blocks
constexpr int SLABS = NBLK / L1BLK;  // 16 slabs per reduce block
constexpr int L1BASE   = 1024;       // ws float offset: L1 partials [row][block]
constexpr int PARTBASE = 16384;      // ws float offset: per-block slabs [block][row]

#define SCHED_FENCE asm volatile("" ::: "memory")
#define WAITVM(n)   asm volatile("s_waitcnt vmcnt(" #n ")" ::: "memory")

typedef __attribute__((address_space(1))) void A1v;
typedef __attribute__((address_space(3))) void A3v;

__device__ __forceinline__ void gload16(const void* g, void* l) {
  // 16B/lane direct global->LDS DMA; LDS dest = uniform base + lane*16.
  __builtin_amdgcn_global_load_lds((const A1v*)g, (A3v*)l, 16, 0, 0);
}

__device__ __forceinline__ short f2bf(float f) {
  return (short)__bfloat16_as_ushort(__float2bfloat16(f));
}

__device__ __forceinline__ float wave_sum64(float x) {
  int t;
  t = __builtin_amdgcn_update_dpp(0, __float_as_int(x), 0x111, 0xf, 0xf, true); x += __int_as_float(t);
  t = __builtin_amdgcn_update_dpp(0, __float_as_int(x), 0x112, 0xf, 0xf, true); x += __int_as_float(t);
  t = __builtin_amdgcn_update_dpp(0, __float_as_int(x), 0x114, 0xf, 0xf, true); x += __int_as_float(t);
  t = __builtin_amdgcn_update_dpp(0, __float_as_int(x), 0x118, 0xf, 0xf, true); x += __int_as_float(t);
  t = __builtin_amdgcn_update_dpp(0, __float_as_int(x), 0x142, 0xf, 0xf, true); x += __int_as_float(t);
  t = __builtin_amdgcn_update_dpp(0, __float_as_int(x), 0x143, 0xf, 0xf, true); x += __int_as_float(t);
  return x;  // lane 63 holds the sum
}

// Stage one 256-px tile into this wave's LDS buffer: 8 pred rows + labels.
// Pred global src is pre-swizzled so that swizzled ds_reads see linear px.
__device__ __forceinline__ void stage_tile(const float* __restrict__ pred,
                                           const int*   __restrict__ lab,
                                           float* predbuf, int* labbuf,
                                           size_t px0, int lane, size_t P) {
  const int lb16 = lane * 16;
#pragma unroll
  for (int c = 0; c < 8; ++c) {
    const int swf = (lb16 ^ ((c & 3) << 5)) >> 2;   // float idx within 1KB row
    gload16(pred + (size_t)c * P + px0 + swf, predbuf + c * TPX);
  }
  gload16(lab + px0 + lane * 4, labbuf);
}

// Compute one tile (8 steps x 2 MFMA) from this wave's LDS buffer.
__device__ __forceinline__ void compute_tile(const float* __restrict__ pbuf,
                                             const int*   __restrict__ lbuf,
                                             int colq, int quad, int ms0, int ms1,
                                             short8 Bconst,
                                             f32x4& acc0, f32x4& acc1) {
  const short ONE = (short)0x3F80;
  const int c  = colq & 7;                              // clamped row for lanes 8..15
  const int swf = ((quad * 32) ^ ((c & 3) << 5)) >> 2;  // swizzled float offset
  const float* pb = pbuf + c * TPX + swf;
  const int*   lb = lbuf + quad * 8;
  const bool isch = (colq < 8);
#pragma unroll
  for (int s = 0; s < STEPS; ++s) {
    const int4 la = *(const int4*)(lb + s * 32);
    const int4 lc = *(const int4*)(lb + s * 32 + 4);
    const float4 x = *(const float4*)(pb + s * 32);       // byte off s*128 (^swz)
    const float4 y = *(const float4*)(pb + s * 32 + 4);   // +16B (h-bit, unswizzled)
    short8 A0, A1, B;
    A0[0] = (la.x == ms0) ? ONE : (short)0;
    A0[1] = (la.y == ms0) ? ONE : (short)0;
    A0[2] = (la.z == ms0) ? ONE : (short)0;
    A0[3] = (la.w == ms0) ? ONE : (short)0;
    A0[4] = (lc.x == ms0) ? ONE : (short)0;
    A0[5] = (lc.y == ms0) ? ONE : (short)0;
    A0[6] = (lc.z == ms0) ? ONE : (short)0;
    A0[7] = (lc.w == ms0) ? ONE : (short)0;
    A1[0] = (la.x == ms1) ? ONE : (short)0;
    A1[1] = (la.y == ms1) ? ONE : (short)0;
    A1[2] = (la.z == ms1) ? ONE : (short)0;
    A1[3] = (la.w == ms1) ? ONE : (short)0;
    A1[4] = (lc.x == ms1) ? ONE : (short)0;
    A1[5] = (lc.y == ms1) ? ONE : (short)0;
    A1[6] = (lc.z == ms1) ? ONE : (short)0;
    A1[7] = (lc.w == ms1) ? ONE : (short)0;
    if (isch) {
      B[0] = f2bf(x.x); B[1] = f2bf(x.y); B[2] = f2bf(x.z); B[3] = f2bf(x.w);
      B[4] = f2bf(y.x); B[5] = f2bf(y.y); B[6] = f2bf(y.z); B[7] = f2bf(y.w);
    } else {
      B = Bconst;
    }
    acc0 = __builtin_amdgcn_mfma_f32_16x16x32_bf16(A0, B, acc0, 0, 0, 0);
    acc1 = __builtin_amdgcn_mfma_f32_16x16x32_bf16(A1, B, acc1, 0, 0, 0);
  }
}

__global__ __launch_bounds__(BLK, 2)
void seg_mfma(const float* __restrict__ pred,
              const int*   __restrict__ lab,
              float*       __restrict__ ws,
              int P) {
  __shared__ __align__(16) float predL[WPB][2][8 * TPX];  // 64 KB
  __shared__ __align__(16) int   labL[WPB][2][TPX];       // 8 KB
  __shared__ float red[WPB][NROWS];                       // 4.6 KB

  const int tid  = threadIdx.x;
  const int wid  = tid >> 6;
  const int lane = tid & 63;
  const int colq = lane & 15;   // D col: 0..7 channel, 8 count, 9..15 unused
  const int quad = lane >> 4;   // k-group (8 px each)
  const int ms0  = colq + 1;    // acc0: segments 1..16
  const int ms1  = colq + 17;   // acc1: segments 17..32

  // XCD-bijective block swizzle (512 % 8 == 0).
  const int bs = (blockIdx.x & 7) * (NBLK / 8) + (blockIdx.x >> 3);
  const int gw = bs * WPB + wid;

  const int spt = (P / TPX) / NWAVES;       // tiles per wave (guarded >= 2)
  const size_t px00 = (size_t)gw * spt * TPX;

  f32x4 acc0 = {0.f, 0.f, 0.f, 0.f};
  f32x4 acc1 = {0.f, 0.f, 0.f, 0.f};

  short8 Bconst;   // col 8 -> bf16 1.0 (counts); cols 9..15 -> 0
  {
    const short v = (colq == 8) ? (short)0x3F80 : (short)0;
#pragma unroll
    for (int i = 0; i < 8; ++i) Bconst[i] = v;
  }

  float* pb0 = &predL[wid][0][0];
  float* pb1 = &predL[wid][1][0];
  int*   lb0 = &labL[wid][0][0];
  int*   lb1 = &labL[wid][1][0];

  // Prologue: fill both buffers (18 DMA instrs in flight).
  stage_tile(pred, lab, pb0, lb0, px00, lane, (size_t)P);
  stage_tile(pred, lab, pb1, lb1, px00 + TPX, lane, (size_t)P);

  for (int t = 0; t < spt; ++t) {
    if (t < spt - 1) { WAITVM(9); } else { WAITVM(0); }  // oldest tile landed
    const float* pb = (t & 1) ? pb1 : pb0;
    const int*   lb = (t & 1) ? lb1 : lb0;
    compute_tile(pb, lb, colq, quad, ms0, ms1, Bconst, acc0, acc1);
    SCHED_FENCE;   // pin ds_read issue before re-staging the same buffer
    if (t + 2 < spt) {
      stage_tile(pred, lab, (t & 1) ? pb1 : pb0, (t & 1) ? lb1 : lb0,
                 px00 + (size_t)(t + 2) * TPX, lane, (size_t)P);
    }
  }

  // D layout (m89/m91-verified): col = lane&15, row = (lane>>4)*4 + reg.
  // acc0 row r -> segment r+1 ; acc1 row r -> segment r+17.
  if (colq < RPS) {
#pragma unroll
    for (int r = 0; r < 4; ++r)
      red[wid][(quad * 4 + r) * RPS + colq] = acc0[r];
#pragma unroll
    for (int r = 0; r < 4; ++r)
      red[wid][(16 + quad * 4 + r) * RPS + colq] = acc1[r];
  }
  __syncthreads();
  for (int v = tid; v < NROWS; v += BLK) {
    float s = 0.f;
#pragma unroll
    for (int w = 0; w < WPB; ++w) s += red[w][v];
    ws[PARTBASE + (size_t)blockIdx.x * NROWS + v] = s;   // plain-store slab
  }
}

// Level-1: block b sums SLABS contiguous slabs (coalesced reads); writes
// TRANSPOSED [row][block] so finish reads 128B-contiguous rows.
__global__ __launch_bounds__(256)
void reduce1(float* __restrict__ ws) {
  const int b = blockIdx.x;
  for (int v = threadIdx.x; v < NROWS; v += 256) {
    float s = 0.f;
#pragma unroll 4
    for (int i = 0; i < SLABS; ++i)
      s += ws[PARTBASE + (size_t)(b * SLABS + i) * NROWS + v];
    ws[L1BASE + (size_t)v * L1BLK + b] = s;
  }
}

// Fallback (C != 8 or bad divisibility): LDS-atomic bins, plain-store slabs.
__global__ __launch_bounds__(BLK)
void seg_gen(const float* __restrict__ pred,
             const int*   __restrict__ lab,
             float*       __restrict__ ws,
             int P, int C) {
  __shared__ float bins[(NSEGF + 1) * RPS];
  const int tid = threadIdx.x;
  for (int i = tid; i < (NSEGF + 1) * RPS; i += BLK) bins[i] = 0.f;
  __syncthreads();
  const int stride = gridDim.x * BLK;
  const int Cc = C < 8 ? C : 8;
  for (int p = blockIdx.x * BLK + tid; p < P; p += stride) {
    int lb = lab[p]; if (lb < 0) lb = 0; if (lb > NSEGF) lb = NSEGF;
    const int o = lb * RPS;
    unsafeAtomicAdd(&bins[o + 8], 1.f);
    for (int c = 0; c < Cc; ++c)
      unsafeAtomicAdd(&bins[o + c], pred[(size_t)c * P + p]);
  }
  __syncthreads();
  for (int i = tid; i < NROWS; i += BLK)
    ws[PARTBASE + (size_t)blockIdx.x * NROWS + i] = bins[RPS + i];
}

__global__ __launch_bounds__(256)
void finish_kernel(const float* __restrict__ ws,
                   const int*   __restrict__ nkp,
                   float*       __restrict__ out,
                   int C) {
  __shared__ float sfin[NROWS];
  __shared__ float sA[NSEGF + 1];
  __shared__ float wsum[4];
  int K = *nkp; if (K > NSEGF) K = NSEGF;
  const int tid = threadIdx.x;
  const int Cc = C < 8 ? C : 8;

  // Level-2 reduce: row v's 32 partials are contiguous (128B) -> coalesced.
  for (int v = tid; v < NROWS; v += 256) {
    const float* r = ws + L1BASE + (size_t)v * L1BLK;
    float s = 0.f;
#pragma unroll
    for (int b = 0; b < L1BLK; ++b) s += r[b];
    sfin[v] = s;
  }
  __syncthreads();
  for (int k = 1 + tid; k <= K; k += 256) {
    float s2 = 0.f;
    for (int c = 0; c < Cc; ++c) {
      const float v = sfin[(k - 1) * RPS + c];
      s2 = fmaf(v, v, s2);
    }
    sA[k] = sfin[(k - 1) * RPS + 8] * s2;
  }
  __syncthreads();

  // All-lane pair loop (R5 lesson: never serialize transcendentals per lane).
  const int npairs = K * (K - 1) / 2;
  float accv = 0.f;
  for (int idx = tid; idx < npairs; idx += 256) {
    int i = 1, rem = idx;
    while (rem >= K - i) { rem -= K - i; ++i; }
    const int j = i + 1 + rem;
    const float ps = sA[i] + sA[j];
    const float d  = fmaxf(3.0f - sqrtf(ps), 0.f);
    accv += logf(fmaf(d, d, 1.f));
  }
  accv = wave_sum64(accv);
  if ((tid & 63) == 63) wsum[tid >> 6] = accv;
  __syncthreads();
  if (tid == 0)
    out[0] = (wsum[0] + wsum[1] + wsum[2] + wsum[3]) * (float)(K - 1) / (float)K;
}

extern "C" void kernel_launch(void* const* d_in, const int* in_sizes, int n_in,
                              void* d_out, int out_size, void* d_ws, size_t ws_size,
                              hipStream_t stream) {
  const float* pred = (const float*)d_in[0];
  const int*   lab  = (const int*)d_in[2];
  const int*   nkp  = (const int*)d_in[3];
  float*       out  = (float*)d_out;
  float*       ws   = (float*)d_ws;

  const int P = in_sizes[2];        // H*W
  const int C = in_sizes[0] / P;    // channels

  const size_t need = (size_t)(PARTBASE + (size_t)NBLK * NROWS) * sizeof(float);
  const int spt = (P / TPX) / NWAVES;
  const bool fast = (C == 8) && (P % (TPX * NWAVES)) == 0 && spt >= 2 &&
                    ws_size >= need;

  if (fast) {
    seg_mfma<<<NBLK, BLK, 0, stream>>>(pred, lab, ws, P);
  } else {
    seg_gen<<<NBLK, BLK, 0, stream>>>(pred, lab, ws, P, C);
  }
  reduce1<<<L1BLK, 256, 0, stream>>>(ws);
  finish_kernel<<<1, 256, 0, stream>>>(ws, nkp, out, C);
}

// Round 14
// 41.601 us; speedup vs baseline: 5.9757x; 1.1224x over previous
//
#include <hip/hip_runtime.h>
#include <hip/hip_bf16.h>
#include <math.h>

// DiscriminationLoss via MFMA (R14):
//   S[k,c] = sum_{p: label[p]=k} pred[c,p],  N[k] = |{p: label[p]=k}|, k=1..32
//   A[k]   = N[k] * sum_c S[k,c]^2
//   L      = sum_{i<j} log(max(3 - sqrt(A_i + A_j), 0)^2 + 1);  out = L*(K-1)/K
//
// R13 lessons: (1) ((c&3)<<5) swizzle left an 8-way bank conflict
// (SQ_LDS_BANK_CONFLICT=4.5M) -- read phases only used 4 of 8 16B slots;
// (2) 78KB LDS -> 2 blocks/CU (occ 20%). R14: proper 3-bit swizzle
// byte^((c&7)<<4) on BOTH sides (DMA source pre-swizzle + ds_read swizzle),
// TPX=128 so LDS=36KB -> 4 blocks/CU / 16 waves/CU, red[] overlaid on the
// wave's own predL after its loop (no cross-wave hazard), 5 DMA/tile with
// counted vmcnt(5) (never 0 in steady state).

typedef __attribute__((ext_vector_type(8))) short short8;
typedef __attribute__((ext_vector_type(4))) float f32x4;

constexpr int NSEGF = 32;            // segments 1..32 (label 0 = background)
constexpr int RPS   = 9;             // 8 channels + count
constexpr int NROWS = NSEGF * RPS;   // 288
constexpr int BLK   = 256;
constexpr int WPB   = 4;
constexpr int NBLK  = 1024;          // 4 blocks/CU co-resident
constexpr int NWAVES= NBLK * WPB;    // 4096 waves
constexpr int TPX   = 128;           // pixels per tile (per wave per buffer)
constexpr int STEPS = TPX / 32;      // 4 dual-MFMA steps per tile
constexpr int L1BLK = 32;            // level-1 reduce blocks
constexpr int SLABS = NBLK / L1BLK;  // 32 slabs per reduce block
constexpr int L1BASE   = 1024;       // ws float offset: L1 partials [row][block]
constexpr int PARTBASE = 16384;      // ws float offset: per-block slabs [block][row]

#define SCHED_FENCE asm volatile("" ::: "memory")
#define WAITVM(n)   asm volatile("s_waitcnt vmcnt(" #n ")" ::: "memory")

typedef __attribute__((address_space(1))) void A1v;
typedef __attribute__((address_space(3))) void A3v;

__device__ __forceinline__ void gload16(const void* g, void* l) {
  // 16B/lane direct global->LDS DMA; LDS dest = uniform base + lane*16.
  __builtin_amdgcn_global_load_lds((const A1v*)g, (A3v*)l, 16, 0, 0);
}

__device__ __forceinline__ short f2bf(float f) {
  return (short)__bfloat16_as_ushort(__float2bfloat16(f));
}

__device__ __forceinline__ float wave_sum64(float x) {
  int t;
  t = __builtin_amdgcn_update_dpp(0, __float_as_int(x), 0x111, 0xf, 0xf, true); x += __int_as_float(t);
  t = __builtin_amdgcn_update_dpp(0, __float_as_int(x), 0x112, 0xf, 0xf, true); x += __int_as_float(t);
  t = __builtin_amdgcn_update_dpp(0, __float_as_int(x), 0x114, 0xf, 0xf, true); x += __int_as_float(t);
  t = __builtin_amdgcn_update_dpp(0, __float_as_int(x), 0x118, 0xf, 0xf, true); x += __int_as_float(t);
  t = __builtin_amdgcn_update_dpp(0, __float_as_int(x), 0x142, 0xf, 0xf, true); x += __int_as_float(t);
  t = __builtin_amdgcn_update_dpp(0, __float_as_int(x), 0x143, 0xf, 0xf, true); x += __int_as_float(t);
  return x;  // lane 63 holds the sum
}

// Stage one 128-px tile: 4 pred DMA (each covers 2 channel rows of 512B)
// + 1 label DMA (32 lanes). Global source pre-swizzled byte^((c&7)<<4).
__device__ __forceinline__ void stage_tile(const float* __restrict__ pred,
                                           const int*   __restrict__ lab,
                                           float* predbuf, int* labbuf,
                                           size_t px0, int lane, size_t P) {
#pragma unroll
  for (int i = 0; i < 4; ++i) {
    const int c   = 2 * i + (lane >> 5);
    const int swb = (((lane & 31) * 16) ^ ((c & 7) << 4));  // byte within 512B row
    gload16(pred + (size_t)c * P + px0 + (swb >> 2), predbuf + i * 256);
  }
  if (lane < 32) gload16(lab + px0 + lane * 4, labbuf);
}

// Compute one tile (4 steps x 2 MFMA) from this wave's LDS buffer.
__device__ __forceinline__ void compute_tile(const float* __restrict__ pbuf,
                                             const int*   __restrict__ lbuf,
                                             int colq, int quad, int ms0, int ms1,
                                             short8 Bconst,
                                             f32x4& acc0, f32x4& acc1) {
  const short ONE = (short)0x3F80;
  const int  c    = colq & 7;            // lanes 8..15 alias c of colq-8 (broadcast)
  const bool isch = (colq < 8);
  const char* prow = (const char*)(pbuf + c * TPX);
  const int*  lb   = lbuf + quad * 8;
#pragma unroll
  for (int s = 0; s < STEPS; ++s) {
    const int4 la = *(const int4*)(lb + s * 32);
    const int4 lc = *(const int4*)(lb + s * 32 + 4);
    const int  b0 = (s * 128 + quad * 32) ^ ((c & 7) << 4);   // swizzled byte
    const float4 x = *(const float4*)(prow + b0);
    const float4 y = *(const float4*)(prow + (b0 ^ 16));
    short8 A0, A1, B;
    A0[0] = (la.x == ms0) ? ONE : (short)0;
    A0[1] = (la.y == ms0) ? ONE : (short)0;
    A0[2] = (la.z == ms0) ? ONE : (short)0;
    A0[3] = (la.w == ms0) ? ONE : (short)0;
    A0[4] = (lc.x == ms0) ? ONE : (short)0;
    A0[5] = (lc.y == ms0) ? ONE : (short)0;
    A0[6] = (lc.z == ms0) ? ONE : (short)0;
    A0[7] = (lc.w == ms0) ? ONE : (short)0;
    A1[0] = (la.x == ms1) ? ONE : (short)0;
    A1[1] = (la.y == ms1) ? ONE : (short)0;
    A1[2] = (la.z == ms1) ? ONE : (short)0;
    A1[3] = (la.w == ms1) ? ONE : (short)0;
    A1[4] = (lc.x == ms1) ? ONE : (short)0;
    A1[5] = (lc.y == ms1) ? ONE : (short)0;
    A1[6] = (lc.z == ms1) ? ONE : (short)0;
    A1[7] = (lc.w == ms1) ? ONE : (short)0;
    if (isch) {
      B[0] = f2bf(x.x); B[1] = f2bf(x.y); B[2] = f2bf(x.z); B[3] = f2bf(x.w);
      B[4] = f2bf(y.x); B[5] = f2bf(y.y); B[6] = f2bf(y.z); B[7] = f2bf(y.w);
    } else {
      B = Bconst;
    }
    acc0 = __builtin_amdgcn_mfma_f32_16x16x32_bf16(A0, B, acc0, 0, 0, 0);
    acc1 = __builtin_amdgcn_mfma_f32_16x16x32_bf16(A1, B, acc1, 0, 0, 0);
  }
}

__global__ __launch_bounds__(BLK, 4)
void seg_mfma(const float* __restrict__ pred,
              const int*   __restrict__ lab,
              float*       __restrict__ ws,
              int P) {
  __shared__ __align__(16) float predL[WPB][2][8 * TPX];  // 32 KB (red overlaid later)
  __shared__ __align__(16) int   labL[WPB][2][TPX];       // 4 KB

  const int tid  = threadIdx.x;
  const int wid  = tid >> 6;
  const int lane = tid & 63;
  const int colq = lane & 15;   // D col: 0..7 channel, 8 count, 9..15 unused
  const int quad = lane >> 4;   // k-group (8 px each)
  const int ms0  = colq + 1;    // acc0: segments 1..16
  const int ms1  = colq + 17;   // acc1: segments 17..32

  // XCD-bijective block swizzle (1024 % 8 == 0).
  const int bs = (blockIdx.x & 7) * (NBLK / 8) + (blockIdx.x >> 3);
  const int gw = bs * WPB + wid;

  const int spt = (P / TPX) / NWAVES;       // tiles per wave (guarded >= 2)
  const size_t px00 = (size_t)gw * spt * TPX;

  f32x4 acc0 = {0.f, 0.f, 0.f, 0.f};
  f32x4 acc1 = {0.f, 0.f, 0.f, 0.f};

  short8 Bconst;   // col 8 -> bf16 1.0 (counts); cols 9..15 -> 0
  {
    const short v = (colq == 8) ? (short)0x3F80 : (short)0;
#pragma unroll
    for (int i = 0; i < 8; ++i) Bconst[i] = v;
  }

  float* pb0 = &predL[wid][0][0];
  float* pb1 = &predL[wid][1][0];
  int*   lb0 = &labL[wid][0][0];
  int*   lb1 = &labL[wid][1][0];

  // Prologue: fill both buffers (10 DMA instrs in flight).
  stage_tile(pred, lab, pb0, lb0, px00, lane, (size_t)P);
  stage_tile(pred, lab, pb1, lb1, px00 + TPX, lane, (size_t)P);

  for (int t = 0; t < spt; ++t) {
    if (t < spt - 1) { WAITVM(5); } else { WAITVM(0); }  // oldest tile landed
    const float* pb = (t & 1) ? pb1 : pb0;
    const int*   lb = (t & 1) ? lb1 : lb0;
    compute_tile(pb, lb, colq, quad, ms0, ms1, Bconst, acc0, acc1);
    SCHED_FENCE;   // pin ds_read issue before re-staging the same buffer
    if (t + 2 < spt) {
      stage_tile(pred, lab, (t & 1) ? pb1 : pb0, (t & 1) ? lb1 : lb0,
                 px00 + (size_t)(t + 2) * TPX, lane, (size_t)P);
    }
  }

  // Per-wave partials overlaid on this wave's OWN predL (loop is done; no
  // cross-wave hazard since buffers are wave-private).
  // D layout (m89/m91-verified): col = lane&15, row = (lane>>4)*4 + reg.
  float* redw = &predL[wid][0][0];
  SCHED_FENCE;
  if (colq < RPS) {
#pragma unroll
    for (int r = 0; r < 4; ++r)
      redw[(quad * 4 + r) * RPS + colq] = acc0[r];
#pragma unroll
    for (int r = 0; r < 4; ++r)
      redw[(16 + quad * 4 + r) * RPS + colq] = acc1[r];
  }
  __syncthreads();
  for (int v = tid; v < NROWS; v += BLK) {
    float s = 0.f;
#pragma unroll
    for (int w = 0; w < WPB; ++w) s += predL[w][0][v];
    ws[PARTBASE + (size_t)blockIdx.x * NROWS + v] = s;   // plain-store slab
  }
}

// Level-1: block b sums SLABS contiguous slabs (coalesced reads); writes
// TRANSPOSED [row][block] so finish reads 128B-contiguous rows.
__global__ __launch_bounds__(256)
void reduce1(float* __restrict__ ws) {
  const int b = blockIdx.x;
  for (int v = threadIdx.x; v < NROWS; v += 256) {
    float s = 0.f;
#pragma unroll 4
    for (int i = 0; i < SLABS; ++i)
      s += ws[PARTBASE + (size_t)(b * SLABS + i) * NROWS + v];
    ws[L1BASE + (size_t)v * L1BLK + b] = s;
  }
}

// Fallback (C != 8 or bad divisibility): LDS-atomic bins, plain-store slabs.
__global__ __launch_bounds__(BLK)
void seg_gen(const float* __restrict__ pred,
             const int*   __restrict__ lab,
             float*       __restrict__ ws,
             int P, int C) {
  __shared__ float bins[(NSEGF + 1) * RPS];
  const int tid = threadIdx.x;
  for (int i = tid; i < (NSEGF + 1) * RPS; i += BLK) bins[i] = 0.f;
  __syncthreads();
  const int stride = gridDim.x * BLK;
  const int Cc = C < 8 ? C : 8;
  for (int p = blockIdx.x * BLK + tid; p < P; p += stride) {
    int lb = lab[p]; if (lb < 0) lb = 0; if (lb > NSEGF) lb = NSEGF;
    const int o = lb * RPS;
    unsafeAtomicAdd(&bins[o + 8], 1.f);
    for (int c = 0; c < Cc; ++c)
      unsafeAtomicAdd(&bins[o + c], pred[(size_t)c * P + p]);
  }
  __syncthreads();
  for (int i = tid; i < NROWS; i += BLK)
    ws[PARTBASE + (size_t)blockIdx.x * NROWS + i] = bins[RPS + i];
}

__global__ __launch_bounds__(256)
void finish_kernel(const float* __restrict__ ws,
                   const int*   __restrict__ nkp,
                   float*       __restrict__ out,
                   int C) {
  __shared__ float sfin[NROWS];
  __shared__ float sA[NSEGF + 1];
  __shared__ float wsum[4];
  int K = *nkp; if (K > NSEGF) K = NSEGF;
  const int tid = threadIdx.x;
  const int Cc = C < 8 ? C : 8;

  // Level-2 reduce: row v's 32 partials are contiguous (128B) -> coalesced.
  for (int v = tid; v < NROWS; v += 256) {
    const float* r = ws + L1BASE + (size_t)v * L1BLK;
    float s = 0.f;
#pragma unroll
    for (int b = 0; b < L1BLK; ++b) s += r[b];
    sfin[v] = s;
  }
  __syncthreads();
  for (int k = 1 + tid; k <= K; k += 256) {
    float s2 = 0.f;
    for (int c = 0; c < Cc; ++c) {
      const float v = sfin[(k - 1) * RPS + c];
      s2 = fmaf(v, v, s2);
    }
    sA[k] = sfin[(k - 1) * RPS + 8] * s2;
  }
  __syncthreads();

  // All-lane pair loop (R5 lesson: never serialize transcendentals per lane).
  const int npairs = K * (K - 1) / 2;
  float accv = 0.f;
  for (int idx = tid; idx < npairs; idx += 256) {
    int i = 1, rem = idx;
    while (rem >= K - i) { rem -= K - i; ++i; }
    const int j = i + 1 + rem;
    const float ps = sA[i] + sA[j];
    const float d  = fmaxf(3.0f - sqrtf(ps), 0.f);
    accv += logf(fmaf(d, d, 1.f));
  }
  accv = wave_sum64(accv);
  if ((tid & 63) == 63) wsum[tid >> 6] = accv;
  __syncthreads();
  if (tid == 0)
    out[0] = (wsum[0] + wsum[1] + wsum[2] + wsum[3]) * (float)(K - 1) / (float)K;
}

extern "C" void kernel_launch(void* const* d_in, const int* in_sizes, int n_in,
                              void* d_out, int out_size, void* d_ws, size_t ws_size,
                              hipStream_t stream) {
  const float* pred = (const float*)d_in[0];
  const int*   lab  = (const int*)d_in[2];
  const int*   nkp  = (const int*)d_in[3];
  float*       out  = (float*)d_out;
  float*       ws   = (float*)d_ws;

  const int P = in_sizes[2];        // H*W
  const int C = in_sizes[0] / P;    // channels

  const size_t need = (size_t)(PARTBASE + (size_t)NBLK * NROWS) * sizeof(float);
  const int spt = (P / TPX) / NWAVES;
  const bool fast = (C == 8) && (P % (TPX * NWAVES)) == 0 && spt >= 2 &&
                    ws_size >= need;

  if (fast) {
    seg_mfma<<<NBLK, BLK, 0, stream>>>(pred, lab, ws, P);
  } else {
    seg_gen<<<NBLK, BLK, 0, stream>>>(pred, lab, ws, P, C);
  }
  reduce1<<<L1BLK, 256, 0, stream>>>(ws);
  finish_kernel<<<1, 256, 0, stream>>>(ws, nkp, out, C);
}